// Round 12
// baseline (102.390 us; speedup 1.0000x reference)
//
#include <hip/hip_runtime.h>
#include <cstddef>
#include <cstdint>

constexpr int BATCH   = 4096;
constexpr int IN_DIM  = 8192;
constexpr int OUT_DIM = 16384;
constexpr int THREADS = 512;                        // 8 waves per block
constexpr int ROWS    = 8;                          // rows per block (4 pairs)
constexpr int PAIRS   = ROWS / 2;                   // 4 pair-steps per block
constexpr int NBLK    = BATCH / ROWS;               // 512 blocks -> 2/CU resident
constexpr int OPT     = 4;                          // neurons per thread per chunk
constexpr int CHUNKS  = OUT_DIM / (THREADS * OPT);  // 8
constexpr int SSTEPS  = (IN_DIM / 4) / THREADS;     // 4 f32x4 loads per row per thread

typedef float    f32x4 __attribute__((ext_vector_type(4)));
typedef uint32_t u32x4 __attribute__((ext_vector_type(4)));

__device__ __forceinline__ uint32_t f2bf(float f) {   // RNE bf16 (x in [0,1))
  uint32_t u = __float_as_uint(f);
  u += 0x7fffu + ((u >> 16) & 1u);
  return u >> 16;
}
__device__ __forceinline__ uint32_t pack_bf(float a, float b) {
  return f2bf(a) | (f2bf(b) << 16);
}
__device__ __forceinline__ float bf_lo(uint32_t u) { return __uint_as_float(u << 16); }
__device__ __forceinline__ float bf_hi(uint32_t u) { return __uint_as_float(u & 0xffff0000u); }

// softmax over 16 gate logits collapsed to (c0, ca, cb, cab); also packs idx pair
__global__ __launch_bounds__(64)
void coef_kernel(const float* __restrict__ weights,
                 const int* __restrict__ idx_a,
                 const int* __restrict__ idx_b,
                 float4* __restrict__ coef,
                 uint32_t* __restrict__ pidx) {
  const int o = blockIdx.x * 64 + threadIdx.x;
  if (o >= OUT_DIM) return;

  const float4* wp = reinterpret_cast<const float4*>(weights + (size_t)o * 16);
  float4 t0 = wp[0], t1 = wp[1], t2 = wp[2], t3 = wp[3];
  float w[16] = { t0.x, t0.y, t0.z, t0.w, t1.x, t1.y, t1.z, t1.w,
                  t2.x, t2.y, t2.z, t2.w, t3.x, t3.y, t3.z, t3.w };
  float m = w[0];
#pragma unroll
  for (int i = 1; i < 16; ++i) m = fmaxf(m, w[i]);
  float p[16]; float s = 0.f;
#pragma unroll
  for (int i = 0; i < 16; ++i) { p[i] = __expf(w[i] - m); s += p[i]; }
  const float inv = 1.0f / s;
  const float GC[16]  = {0,0,0,0, 0,0,0,0, 1,1,1,1, 1,1,1,1};
  const float GA[16]  = {0,0,1,1, 0,0,1,1, -1,-1,0,0, -1,-1,0,0};
  const float GB[16]  = {0,0,0,0, 1,1,1,1, -1,-1,-1,-1, 0,0,0,0};
  const float GAB[16] = {0,1,-1,0, -1,0,-2,-1, 1,2,0,1, 0,1,-1,0};
  float c0 = 0.f, ca = 0.f, cb = 0.f, cab = 0.f;
#pragma unroll
  for (int i = 0; i < 16; ++i) {
    c0 += p[i] * GC[i]; ca += p[i] * GA[i];
    cb += p[i] * GB[i]; cab += p[i] * GAB[i];
  }
  coef[o] = make_float4(c0 * inv, ca * inv, cb * inv, cab * inv);
  pidx[o] = (uint32_t)idx_a[o] | ((uint32_t)idx_b[o] << 16);
}

// 2-row affine eval from one packed bf16-pair of a and b; returns {lo-row, hi-row}
__device__ __forceinline__ float2 eval2(float4 c, uint32_t ga, uint32_t gb) {
  const float a0 = bf_lo(ga), b0 = bf_lo(gb);
  const float a1 = bf_hi(ga), b1 = bf_hi(gb);
  float2 r;
  r.x = fmaf(fmaf(c.w, a0, c.z), b0, fmaf(c.y, a0, c.x));
  r.y = fmaf(fmaf(c.w, a1, c.z), b1, fmaf(c.y, a1, c.x));
  return r;
}

__global__ __launch_bounds__(THREADS, 4)            // VGPR<=128; LDS gives 2 blocks/CU
void logic_main(const float* __restrict__ x,
                const float4* __restrict__ coef,
                const uint32_t* __restrict__ pidx,
                float* __restrict__ out) {
  // double-buffered pair-packed segments: seg[i] = bf(rowLo[i]) | bf(rowHi[i])<<16
  __shared__ uint32_t seg0[IN_DIM];                 // 32 KB
  __shared__ uint32_t seg1[IN_DIM];                 // 32 KB  (total 64 KB -> 2 blocks/CU)

  const int t    = threadIdx.x;
  const int row0 = blockIdx.x * ROWS;

  f32x4 la[SSTEPS], lb[SSTEPS];                     // in-flight next-pair rows (32 VGPR)

  // ---- prologue: load + pack pair 0 into seg0 ----
  {
    const f32x4* __restrict__ rA =
        reinterpret_cast<const f32x4*>(x + (size_t)row0 * IN_DIM);
    const f32x4* __restrict__ rB =
        reinterpret_cast<const f32x4*>(x + (size_t)(row0 + 1) * IN_DIM);
#pragma unroll
    for (int s = 0; s < SSTEPS; ++s) {
      const int q = s * THREADS + t;
      la[s] = rA[q]; lb[s] = rB[q];
    }
#pragma unroll
    for (int s = 0; s < SSTEPS; ++s) {
      const int q = s * THREADS + t;
      u32x4 pk;
      pk.x = pack_bf(la[s].x, lb[s].x);
      pk.y = pack_bf(la[s].y, lb[s].y);
      pk.z = pack_bf(la[s].z, lb[s].z);
      pk.w = pack_bf(la[s].w, lb[s].w);
      *reinterpret_cast<u32x4*>(&seg0[4 * q]) = pk;
    }
  }
  __syncthreads();

  for (int p = 0; p < PAIRS; ++p) {
    const int bLo = row0 + 2 * p;
    const uint32_t* __restrict__ seg = (p & 1) ? seg1 : seg0;
    uint32_t* __restrict__ nxt = (p & 1) ? seg0 : seg1;

    // ---- ISSUE next pair's loads early: HBM latency+BW hide under compute ----
    if (p + 1 < PAIRS) {
      const f32x4* __restrict__ rA =
          reinterpret_cast<const f32x4*>(x + (size_t)(bLo + 2) * IN_DIM);
      const f32x4* __restrict__ rB =
          reinterpret_cast<const f32x4*>(x + (size_t)(bLo + 3) * IN_DIM);
#pragma unroll
      for (int s = 0; s < SSTEPS; ++s) {
        const int q = s * THREADS + t;
        la[s] = rA[q]; lb[s] = rB[q];
      }
    }

    // ---- compute current pair: gather + affine + stores ----
    {
      // prefetch chunk-0 operands
      int o0 = t * OPT;
      int4   pi = *reinterpret_cast<const int4*>(pidx + o0);
      float4 c0 = coef[o0 + 0], c1 = coef[o0 + 1],
             c2 = coef[o0 + 2], c3 = coef[o0 + 3];

#pragma unroll 2
      for (int ch = 0; ch < CHUNKS; ++ch) {
        const int o = ch * (THREADS * OPT) + t * OPT;

        const uint32_t i0a = (uint32_t)pi.x & 0xffffu, i0b = (uint32_t)pi.x >> 16;
        const uint32_t i1a = (uint32_t)pi.y & 0xffffu, i1b = (uint32_t)pi.y >> 16;
        const uint32_t i2a = (uint32_t)pi.z & 0xffffu, i2b = (uint32_t)pi.z >> 16;
        const uint32_t i3a = (uint32_t)pi.w & 0xffffu, i3b = (uint32_t)pi.w >> 16;

        const uint32_t g0a = seg[i0a], g0b = seg[i0b];
        const uint32_t g1a = seg[i1a], g1b = seg[i1b];
        const uint32_t g2a = seg[i2a], g2b = seg[i2b];
        const uint32_t g3a = seg[i3a], g3b = seg[i3b];

        const float2 e0 = eval2(c0, g0a, g0b);
        const float2 e1 = eval2(c1, g1a, g1b);
        const float2 e2 = eval2(c2, g2a, g2b);
        const float2 e3 = eval2(c3, g3a, g3b);

        f32x4 resLo, resHi;
        resLo.x = e0.x; resLo.y = e1.x; resLo.z = e2.x; resLo.w = e3.x;
        resHi.x = e0.y; resHi.y = e1.y; resHi.z = e2.y; resHi.w = e3.y;

        if (ch + 1 < CHUNKS) {
          const int on = o + THREADS * OPT;
          pi = *reinterpret_cast<const int4*>(pidx + on);
          c0 = coef[on + 0]; c1 = coef[on + 1];
          c2 = coef[on + 2]; c3 = coef[on + 3];
        }

        *reinterpret_cast<f32x4*>(out + (size_t)(bLo + 0) * OUT_DIM + o) = resLo;
        *reinterpret_cast<f32x4*>(out + (size_t)(bLo + 1) * OUT_DIM + o) = resHi;
      }
    }

    // ---- WRITE next pair into the other segment (loads completed under compute) ----
    if (p + 1 < PAIRS) {
#pragma unroll
      for (int s = 0; s < SSTEPS; ++s) {
        const int q = s * THREADS + t;
        u32x4 pk;
        pk.x = pack_bf(la[s].x, lb[s].x);
        pk.y = pack_bf(la[s].y, lb[s].y);
        pk.z = pack_bf(la[s].z, lb[s].z);
        pk.w = pack_bf(la[s].w, lb[s].w);
        *reinterpret_cast<u32x4*>(&nxt[4 * q]) = pk;
      }
      __syncthreads();   // one barrier per pair-step
    }
  }
}

extern "C" void kernel_launch(void* const* d_in, const int* in_sizes, int n_in,
                              void* d_out, int out_size, void* d_ws, size_t ws_size,
                              hipStream_t stream) {
  const float* x       = (const float*)d_in[0];
  const float* weights = (const float*)d_in[1];
  const int*   idx_a   = (const int*)d_in[2];
  const int*   idx_b   = (const int*)d_in[3];
  float*       out     = (float*)d_out;

  float4*   coef = (float4*)d_ws;                                   // 256 KB
  uint32_t* pidx = (uint32_t*)((char*)d_ws + (size_t)OUT_DIM * 16); // +64 KB

  coef_kernel<<<OUT_DIM / 64, 64, 0, stream>>>(weights, idx_a, idx_b, coef, pidx);
  logic_main<<<NBLK, THREADS, 0, stream>>>(x, coef, pidx, out);
}